// Round 1
// 2791.571 us; speedup vs baseline: 1.6781x; 1.6781x over previous
//
#include <hip/hip_runtime.h>
#include <math.h>

// Problem constants
#define Bc 2
#define Lc 2048
#define Dc 4096
#define DZc 1024
#define Hc 16
#define HDc 64

// Output layout (flat float32, in reference return order)
#define OFF_Z     16777216L    // (2,2048,4096)
#define OFF_KR    20971520L    // (2,2048,1024)
#define OFF_ATTN  25165824L    // (2,16,2048,2048)
#define OFF_SC    159383552L   // (2,16,2048,2048)

typedef __bf16 bf16x8 __attribute__((ext_vector_type(8)));
typedef unsigned short us8 __attribute__((ext_vector_type(8)));
typedef float f32x4 __attribute__((ext_vector_type(4)));

// Split fp32 -> bf16 hi (truncate) + bf16 lo (exact residual truncated).
// a ~= hi + lo with |a - hi - lo| <= 2^-16 |a|.
__device__ __forceinline__ void split8(const float* __restrict__ f, us8& hi, us8& lo)
{
#pragma unroll
    for (int j = 0; j < 8; ++j) {
        unsigned u = __float_as_uint(f[j]);
        hi[j] = (unsigned short)(u >> 16);
        float hf = __uint_as_float(u & 0xFFFF0000u);
        lo[j] = (unsigned short)(__float_as_uint(f[j] - hf) >> 16);
    }
}

// bf16x3 (NPROD=3) / bf16x4 (NPROD=4) split-precision MFMA GEMM.
// C = scale*(A@B) (+bias), optional transB, optional causal epilogue,
// optional batching: base = (bz/Hdiv)*s1 + (bz%Hdiv)*s2 for A/B/C.
// BM=128 fixed, BN in {128,64}; K and M multiples of 32/128; N multiple of BN.
//
// LDS layout per matrix, per half (hi/lo): [kslot 0..3][row 0..R-1] 16B slots,
// slot holds bf16 for k = kslot*8 + 0..7 of one row. Row-within-16 is XOR-swizzled
// by (kslot<<2) so both ds_write_b128 staging and ds_read_b128 frag reads are
// <=2-way per 16-lane phase (free, m136).
template<int BN, int NPROD>
__global__ __launch_bounds__(256, 2) void gemm_bx3(
    const float* __restrict__ A, const float* __restrict__ Bp,
    const float* __restrict__ bias, float* __restrict__ C,
    int M, int N, int K, int lda, int ldb, int ldc,
    long sA1, long sA2, long sB1, long sB2, long sC1, long sC2,
    int Hdiv, int transB, int causal, float scale, float maskval)
{
    constexpr int BM = 128;
    constexpr int MR = (BN == 128) ? 4 : 2;   // 16-row frags per wave
    constexpr int NR = 4;                      // 16-col frags per wave

    __shared__ __align__(16) unsigned short smem[64 * (BM + BN)];
    unsigned short* sAhi = smem;
    unsigned short* sAlo = smem + 32 * BM;
    unsigned short* sBhi = smem + 64 * BM;
    unsigned short* sBlo = smem + 64 * BM + 32 * BN;

    const int bz = blockIdx.z;
    const float* Ab = A + (long)(bz / Hdiv) * sA1 + (long)(bz % Hdiv) * sA2;
    const float* Bb = Bp + (long)(bz / Hdiv) * sB1 + (long)(bz % Hdiv) * sB2;
    float* Cb = C + (long)(bz / Hdiv) * sC1 + (long)(bz % Hdiv) * sC2;

    const int m0 = blockIdx.y * BM;
    const int n0 = blockIdx.x * BN;
    const int t  = threadIdx.x;

    // Fully-masked causal tile: skip compute, just fill.
    if (causal && n0 > m0 + BM - 1) {
#pragma unroll
        for (int e = 0; e < BM * BN / 256; ++e) {
            int i = e * 256 + t;
            int r = i / BN, c = i % BN;
            Cb[(long)(m0 + r) * ldc + (n0 + c)] = maskval;
        }
        return;
    }

    const int w  = t >> 6;        // wave id
    const int l  = t & 63;        // lane
    const int lr = l & 15;        // frag row/col within 16
    const int lk = l >> 4;        // frag kslot (k = 8*lk + j), also C row-group
    const int wm0 = (BN == 128) ? (w >> 1) * 64 : w * 32;
    const int wn0 = (BN == 128) ? (w & 1) * 64 : 0;

    // frag read bases (16B-slot index *8 ushorts); +i*128 walks 16-row blocks
    const int abase = (lk * BM + wm0 + (lr ^ (lk << 2))) * 8;
    const int bbase = (lk * BN + wn0 + (lr ^ (lk << 2))) * 8;

    f32x4 acc[MR][NR] = {};

    for (int k0 = 0; k0 < K; k0 += 32) {
        // ---- stage A (row-major MxK, k-contiguous): BM*4 slot-tasks ----
#pragma unroll
        for (int task = 0; task < BM / 64; ++task) {
            int id = task * 256 + t;
            int row = id >> 2, ks = id & 3;
            const float* p = Ab + (long)(m0 + row) * lda + (k0 + ks * 8);
            float f[8];
            *(float4*)&f[0] = *(const float4*)p;
            *(float4*)&f[4] = *(const float4*)(p + 4);
            us8 hi, lo;
            split8(f, hi, lo);
            int slot = ks * BM + ((row & ~15) | ((row & 15) ^ (ks << 2)));
            *(us8*)&sAhi[slot * 8] = hi;
            *(us8*)&sAlo[slot * 8] = lo;
        }
        // ---- stage B ----
        if (transB) {
            // B is [N][K] row-major: same pattern as A
#pragma unroll
            for (int task = 0; task < BN / 64; ++task) {
                int id = task * 256 + t;
                int row = id >> 2, ks = id & 3;
                const float* p = Bb + (long)(n0 + row) * ldb + (k0 + ks * 8);
                float f[8];
                *(float4*)&f[0] = *(const float4*)p;
                *(float4*)&f[4] = *(const float4*)(p + 4);
                us8 hi, lo;
                split8(f, hi, lo);
                int slot = ks * BN + ((row & ~15) | ((row & 15) ^ (ks << 2)));
                *(us8*)&sBhi[slot * 8] = hi;
                *(us8*)&sBlo[slot * 8] = lo;
            }
        } else {
            // B is [K][N] row-major: per-column k-gather; each j-iteration is a
            // coalesced 256B wave access (consecutive lanes -> consecutive col).
#pragma unroll
            for (int task = 0; task < BN / 64; ++task) {
                int id = task * 256 + t;
                int col = id % BN, ks = id / BN;
                const float* p = Bb + (long)(k0 + ks * 8) * ldb + (n0 + col);
                float f[8];
#pragma unroll
                for (int j = 0; j < 8; ++j) f[j] = p[(long)j * ldb];
                us8 hi, lo;
                split8(f, hi, lo);
                int slot = ks * BN + ((col & ~15) | ((col & 15) ^ (ks << 2)));
                *(us8*)&sBhi[slot * 8] = hi;
                *(us8*)&sBlo[slot * 8] = lo;
            }
        }
        __syncthreads();

        // ---- fragment loads (ds_read_b128) ----
        us8 avh[MR], avl[MR], bvh[NR], bvl[NR];
#pragma unroll
        for (int i = 0; i < MR; ++i) {
            avh[i] = *(const us8*)&sAhi[abase + i * 128];
            avl[i] = *(const us8*)&sAlo[abase + i * 128];
        }
#pragma unroll
        for (int j = 0; j < NR; ++j) {
            bvh[j] = *(const us8*)&sBhi[bbase + j * 128];
            bvl[j] = *(const us8*)&sBlo[bbase + j * 128];
        }

        // ---- 3 (or 4) MFMA products per frag pair ----
#pragma unroll
        for (int i = 0; i < MR; ++i) {
            bf16x8 ah = __builtin_bit_cast(bf16x8, avh[i]);
            bf16x8 al = __builtin_bit_cast(bf16x8, avl[i]);
#pragma unroll
            for (int j = 0; j < NR; ++j) {
                bf16x8 bh = __builtin_bit_cast(bf16x8, bvh[j]);
                bf16x8 bl = __builtin_bit_cast(bf16x8, bvl[j]);
                acc[i][j] = __builtin_amdgcn_mfma_f32_16x16x32_bf16(ah, bh, acc[i][j], 0, 0, 0);
                acc[i][j] = __builtin_amdgcn_mfma_f32_16x16x32_bf16(ah, bl, acc[i][j], 0, 0, 0);
                acc[i][j] = __builtin_amdgcn_mfma_f32_16x16x32_bf16(al, bh, acc[i][j], 0, 0, 0);
                if constexpr (NPROD == 4)
                    acc[i][j] = __builtin_amdgcn_mfma_f32_16x16x32_bf16(al, bl, acc[i][j], 0, 0, 0);
            }
        }
        __syncthreads();
    }

    // Epilogue. C/D layout: col = lane&15, row = (lane>>4)*4 + reg (m89/m91).
#pragma unroll
    for (int i = 0; i < MR; ++i) {
        const int mrow = m0 + wm0 + i * 16 + lk * 4;
#pragma unroll
        for (int j = 0; j < NR; ++j) {
            const int n = n0 + wn0 + j * 16 + lr;
            const float bv = bias ? bias[n] : 0.0f;
#pragma unroll
            for (int r = 0; r < 4; ++r) {
                float v = acc[i][j][r] * scale + bv;
                if (causal && n > mrow + r) v = maskval;
                Cb[(long)(mrow + r) * ldc + n] = v;
            }
        }
    }
}

// RoPE over (B,L,H,64): out[i] = x[i]*cos - x[i+32]*sin ; out[i+32] = x[i+32]*cos + x[i]*sin
__global__ __launch_bounds__(256) void rope_kernel(
    const float* in, int in_ld, float* out1, int out1_ld, float* out2, int out2_ld)
{
    int t = blockIdx.x * 256 + threadIdx.x;   // B*L*H*32 = 2,097,152 threads
    int i = t & 31;
    int h = (t >> 5) & 15;
    int l = (t >> 9) & 2047;
    int b = t >> 20;
    long row = (long)b * Lc + l;

    float inv_freq = powf(10000.0f, -(float)i * (1.0f / 32.0f));
    float ang = (float)l * inv_freq;
    float s, c;
    sincosf(ang, &s, &c);

    long i1 = row * in_ld + h * 64 + i;
    long i2 = i1 + 32;
    float x1 = in[i1], x2 = in[i2];
    float o1 = x1 * c - x2 * s;
    float o2 = x2 * c + x1 * s;
    long o1a = row * out1_ld + h * 64 + i;
    out1[o1a] = o1;
    out1[o1a + 32] = o2;
    if (out2) {
        long o2a = row * out2_ld + h * 64 + i;
        out2[o2a] = o1;
        out2[o2a + 32] = o2;
    }
}

// Row softmax over 2048-wide rows. One block (256 threads, 8 elems/thread) per row.
__global__ __launch_bounds__(256) void softmax_kernel(
    const float* __restrict__ S, float* __restrict__ P)
{
    long row = blockIdx.x;
    const float* sr = S + row * Lc;
    float* pr = P + row * Lc;
    int t = threadIdx.x;

    float v[8];
    float m = -3.4e38f;
#pragma unroll
    for (int e = 0; e < 8; ++e) { v[e] = sr[t + e * 256]; m = fmaxf(m, v[e]); }
#pragma unroll
    for (int off = 32; off >= 1; off >>= 1) m = fmaxf(m, __shfl_xor(m, off));
    __shared__ float redm[4], reds[4];
    int wave = t >> 6;
    if ((t & 63) == 0) redm[wave] = m;
    __syncthreads();
    m = fmaxf(fmaxf(redm[0], redm[1]), fmaxf(redm[2], redm[3]));

    float s = 0.0f;
#pragma unroll
    for (int e = 0; e < 8; ++e) { v[e] = __expf(v[e] - m); s += v[e]; }
#pragma unroll
    for (int off = 32; off >= 1; off >>= 1) s += __shfl_xor(s, off);
    if ((t & 63) == 0) reds[wave] = s;
    __syncthreads();
    s = reds[0] + reds[1] + reds[2] + reds[3];
    float inv = 1.0f / s;
#pragma unroll
    for (int e = 0; e < 8; ++e) pr[t + e * 256] = v[e] * inv;
}

extern "C" void kernel_launch(void* const* d_in, const int* in_sizes, int n_in,
                              void* d_out, int out_size, void* d_ws, size_t ws_size,
                              hipStream_t stream)
{
    const float* x        = (const float*)d_in[0];
    const float* W_latent = (const float*)d_in[1];
    const float* W_q_down = (const float*)d_in[2];
    const float* b_q_down = (const float*)d_in[3];
    const float* W_q_up   = (const float*)d_in[4];
    const float* W_k_up   = (const float*)d_in[5];
    const float* W_v_up   = (const float*)d_in[6];
    const float* W_x_rope = (const float*)d_in[7];
    const float* W_k_rope = (const float*)d_in[8];
    const float* W_o      = (const float*)d_in[9];

    float* out       = (float*)d_out;
    float* z_out     = out + OFF_Z;
    float* kr_out    = out + OFF_KR;
    float* attn_out  = out + OFF_ATTN;
    float* sc_out    = out + OFF_SC;

    // Workspace layout (floats). q_lat aliased with head_out (lifetimes disjoint).
    float* ws   = (float*)d_ws;
    float* qlat = ws;                       // 4,194,304
    float* qcat = ws + 4194304;             // 8,388,608  (B,L,2048): [query | q_rope]
    float* kcat = qcat + 8388608;           // 8,388,608  (B,L,2048): [key_nope | key_rope]
    float* val  = kcat + 8388608;           // 4,194,304  (B,L,1024)
    float* ho   = qlat;                     // alias: q_lat dead before ho written
    // total: 25,165,824 floats = 96 MB <= ws_size

    const int M = Bc * Lc;  // 4096

    auto gemm = [&](int bn, int np, const float* A, const float* Bp, const float* bias, float* C,
                    int Mm, int N, int K, int lda, int ldb, int ldc,
                    long sA1, long sA2, long sB1, long sB2, long sC1, long sC2,
                    int Hdiv, int batch, int transB, int causal, float scale, float maskval) {
        dim3 g(N / bn, Mm / 128, batch);
        if (bn == 128 && np == 3)
            gemm_bx3<128, 3><<<g, dim3(256), 0, stream>>>(A, Bp, bias, C, Mm, N, K, lda, ldb, ldc,
                sA1, sA2, sB1, sB2, sC1, sC2, Hdiv, transB, causal, scale, maskval);
        else if (bn == 128)
            gemm_bx3<128, 4><<<g, dim3(256), 0, stream>>>(A, Bp, bias, C, Mm, N, K, lda, ldb, ldc,
                sA1, sA2, sB1, sB2, sC1, sC2, Hdiv, transB, causal, scale, maskval);
        else
            gemm_bx3<64, 4><<<g, dim3(256), 0, stream>>>(A, Bp, bias, C, Mm, N, K, lda, ldb, ldc,
                sA1, sA2, sB1, sB2, sC1, sC2, Hdiv, transB, causal, scale, maskval);
    };

    // 1. z = x @ W_latent                        -> d_out z region
    gemm(128, 3, x, W_latent, nullptr, z_out, M, DZc, Dc, Dc, DZc, DZc,
         0, 0, 0, 0, 0, 0, 1, 1, 0, 0, 1.0f, 0.0f);
    // 2. q_lat = x @ W_q_down + b_q_down         -> ws
    gemm(128, 3, x, W_q_down, b_q_down, qlat, M, DZc, Dc, Dc, DZc, DZc,
         0, 0, 0, 0, 0, 0, 1, 1, 0, 0, 1.0f, 0.0f);
    // 3. kr_pre = x @ W_k_rope                   -> kcat cols [1024:2048]
    gemm(128, 3, x, W_k_rope, nullptr, kcat + 1024, M, DZc, Dc, Dc, DZc, 2048,
         0, 0, 0, 0, 0, 0, 1, 1, 0, 0, 1.0f, 0.0f);
    // 4. rope(k): in-place in kcat + copy to d_out key_rope
    rope_kernel<<<dim3(8192), dim3(256), 0, stream>>>(kcat + 1024, 2048, kcat + 1024, 2048, kr_out, 1024);
    // 5. key_nope = z @ W_k_up                   -> kcat cols [0:1024]
    gemm(128, 3, z_out, W_k_up, nullptr, kcat, M, DZc, DZc, DZc, DZc, 2048,
         0, 0, 0, 0, 0, 0, 1, 1, 0, 0, 1.0f, 0.0f);
    // 6. value = z @ W_v_up                      -> ws
    gemm(128, 3, z_out, W_v_up, nullptr, val, M, DZc, DZc, DZc, DZc, DZc,
         0, 0, 0, 0, 0, 0, 1, 1, 0, 0, 1.0f, 0.0f);
    // 7. query = q_lat @ W_q_up                  -> qcat cols [0:1024]
    gemm(128, 3, qlat, W_q_up, nullptr, qcat, M, DZc, DZc, DZc, DZc, 2048,
         0, 0, 0, 0, 0, 0, 1, 1, 0, 0, 1.0f, 0.0f);
    // 8. qr_pre = q_lat @ W_x_rope               -> qcat cols [1024:2048]
    gemm(128, 3, qlat, W_x_rope, nullptr, qcat + 1024, M, DZc, DZc, DZc, DZc, 2048,
         0, 0, 0, 0, 0, 0, 1, 1, 0, 0, 1.0f, 0.0f);
    // 9. rope(q): in-place in qcat
    rope_kernel<<<dim3(8192), dim3(256), 0, stream>>>(qcat + 1024, 2048, qcat + 1024, 2048, nullptr, 0);
    // 10. scores = Q @ K^T / sqrt(128), causal -1e6   (head h = contiguous 128 dims of concat)
    gemm(128, 3, qcat, kcat, nullptr, sc_out, Lc, Lc, 2 * HDc, 2048, 2048, Lc,
         (long)Lc * 2048, 128, (long)Lc * 2048, 128, (long)Hc * Lc * Lc, (long)Lc * Lc,
         Hc, Bc * Hc, 1, 1, 0.08838834764831845f, -1e6f);
    // 11. attn_weights = softmax(scores)
    softmax_kernel<<<dim3(Bc * Hc * Lc), dim3(256), 0, stream>>>(sc_out, attn_out);
    // 12. head_out = scores @ value   (reference uses masked scores, NOT attn_weights)
    //     4-product split: A has exact-split -1e6 mask values, keep dropped-term tiny.
    gemm(64, 4, sc_out, val, nullptr, ho, Lc, HDc, Lc, Lc, DZc, DZc,
         (long)Hc * Lc * Lc, (long)Lc * Lc, (long)Lc * DZc, 64, (long)Lc * DZc, 64,
         Hc, Bc * Hc, 0, 0, 1.0f, 0.0f);
    // 13. out = head_out @ W_o   (4-product: A magnitudes ~1e7 from masked scores)
    gemm(128, 4, ho, W_o, nullptr, out, M, Dc, DZc, DZc, Dc, Dc,
         0, 0, 0, 0, 0, 0, 1, 1, 0, 0, 1.0f, 0.0f);
}

// Round 2
// 2195.028 us; speedup vs baseline: 2.1342x; 1.2718x over previous
//
#include <hip/hip_runtime.h>
#include <math.h>

// Problem constants
#define Bc 2
#define Lc 2048
#define Dc 4096
#define DZc 1024
#define Hc 16
#define HDc 64

// Output layout (flat float32, in reference return order)
#define OFF_Z     16777216L    // (2,2048,4096)
#define OFF_KR    20971520L    // (2,2048,1024)
#define OFF_ATTN  25165824L    // (2,16,2048,2048)
#define OFF_SC    159383552L   // (2,16,2048,2048)

typedef __bf16 bf16x8 __attribute__((ext_vector_type(8)));
typedef unsigned short us8 __attribute__((ext_vector_type(8)));
typedef float f32x4 __attribute__((ext_vector_type(4)));

// Split fp32 -> bf16 hi (truncate) + bf16 lo (truncated exact residual).
__device__ __forceinline__ void split1(float v, unsigned short& h, unsigned short& l)
{
    unsigned u = __float_as_uint(v);
    h = (unsigned short)(u >> 16);
    float r = v - __uint_as_float(u & 0xFFFF0000u);
    l = (unsigned short)(__float_as_uint(r) >> 16);
}

__device__ __forceinline__ void split8(const float* f, us8& hi, us8& lo)
{
#pragma unroll
    for (int j = 0; j < 8; ++j) {
        unsigned short h, l;
        split1(f[j], h, l);
        hi[j] = h; lo[j] = l;
    }
}

// async global->LDS, 16B per lane (global_load_lds_dwordx4).
// LDS dest is wave-uniform base + lane*16; global addr is per-lane.
__device__ __forceinline__ void gload16(const unsigned short* g, unsigned short* l)
{
    __builtin_amdgcn_global_load_lds(
        (const __attribute__((address_space(1))) void*)g,
        (__attribute__((address_space(3))) void*)l, 16, 0, 0);
}

// ---------------------------------------------------------------------------
// bf16 hi/lo split-precision MFMA GEMM, all-transB (B pre-transposed to [N][K]).
// C = scale*(A@B^T-of-[N][K]) (+bias), optional causal epilogue, batching via
// base = (bz/Hdiv)*s1 + (bz%Hdiv)*s2. Up to 3 output "segments" along N
// (seg = n >> segshift), each with its own fp32 / bf16-pair sinks.
// AMODE 0: A is pre-split bf16 hi/lo, staged with global_load_lds.
// AMODE 1: A is fp32, reg-staged + split in-kernel (for the 537MB scores matrix).
// BM=128, BK=32, 4 waves. LDS 32KB (BN=128) -> ~3 blocks/CU.
// Staging uses slot-XOR pre-swizzle on the GLOBAL source (linear LDS dest,
// same XOR on ds_read) so frag reads are <=4-way conflicted.
// ---------------------------------------------------------------------------
template<int BN, int NPROD, int AMODE>
__global__ __launch_bounds__(256, 2) void gemm_hl(
    const unsigned short* __restrict__ Ahi, const unsigned short* __restrict__ Alo,
    const float* __restrict__ Af,
    const unsigned short* __restrict__ Bhi, const unsigned short* __restrict__ Blo,
    float* __restrict__ Cf0, unsigned short* __restrict__ Chi0, unsigned short* __restrict__ Clo0,
    const float* __restrict__ bias0, int ldc0,
    float* __restrict__ Cf1, unsigned short* __restrict__ Chi1, unsigned short* __restrict__ Clo1,
    const float* __restrict__ bias1, int ldc1,
    float* __restrict__ Cf2, unsigned short* __restrict__ Chi2, unsigned short* __restrict__ Clo2,
    const float* __restrict__ bias2, int ldc2,
    int M, int N, int K, int lda, int ldb,
    long sA1, long sA2, long sB1, long sB2, long sC1, long sC2,
    int Hdiv, int causal, float scale, float maskval, int segshift)
{
    constexpr int BM = 128, BK = 32;
    constexpr int MR = (BN == 128) ? 4 : 2;
    constexpr int NR = 4;
    constexpr int AISS = 2;                       // A gload issues per wave per buffer
    constexpr int BISS = (BN == 128) ? 2 : 1;

    __shared__ __align__(16) unsigned short sA[2][BM * BK];   // [hi/lo][slots]
    __shared__ __align__(16) unsigned short sB[2][BN * BK];

    const int bz = blockIdx.z;
    const long abase = (long)(bz / Hdiv) * sA1 + (long)(bz % Hdiv) * sA2;
    const long bbase = (long)(bz / Hdiv) * sB1 + (long)(bz % Hdiv) * sB2;
    const long cbase = (long)(bz / Hdiv) * sC1 + (long)(bz % Hdiv) * sC2;

    const int m0 = blockIdx.y * BM;
    const int n0 = blockIdx.x * BN;
    const int t  = threadIdx.x;

    // segment select (a 128-wide tile never straddles a 1024-aligned segment)
    const int seg = n0 >> segshift;
    float* Cf; unsigned short* Chi; unsigned short* Clo; const float* bias; int ldc;
    if (seg == 0)      { Cf = Cf0; Chi = Chi0; Clo = Clo0; bias = bias0; ldc = ldc0; }
    else if (seg == 1) { Cf = Cf1; Chi = Chi1; Clo = Clo1; bias = bias1; ldc = ldc1; }
    else               { Cf = Cf2; Chi = Chi2; Clo = Clo2; bias = bias2; ldc = ldc2; }
    const int ncol0 = n0 - (seg << segshift);

    // Fully-masked causal tile: fill only.
    if (causal && n0 > m0 + BM - 1) {
        unsigned short mh, ml; split1(maskval, mh, ml);
        for (int e = 0; e < BM * BN / 256; ++e) {
            int i = e * 256 + t;
            int r = i / BN, c = i % BN;
            long co = cbase + (long)(m0 + r) * ldc + (ncol0 + c);
            if (Cf)  Cf[co] = maskval;
            if (Chi) { Chi[co] = mh; Clo[co] = ml; }
        }
        return;
    }

    const int w  = t >> 6, l = t & 63;
    const int lr = l & 15, lk = l >> 4;
    const int wm0 = (BN == 128) ? (w >> 1) * 64 : w * 32;
    const int wn0 = (BN == 128) ? (w & 1) * 64 : 0;

    // staging per-lane global element offsets (excl. k0); slot-XOR pre-swizzle
    long offA[AISS]; long offB[BISS];
    const float* gA[2];
    if constexpr (AMODE == 0) {
#pragma unroll
        for (int jj = 0; jj < AISS; ++jj) {
            int j = w * AISS + jj;
            int r = j * 16 + (l >> 2);
            int ks = (l & 3) ^ (r & 3);
            offA[jj] = abase + (long)(m0 + r) * lda + ks * 8;
        }
    } else {
#pragma unroll
        for (int e = 0; e < 2; ++e) {
            int s = e * 256 + t;
            int r = s >> 2, ks = s & 3;
            gA[e] = Af + abase + (long)(m0 + r) * lda + ks * 8;
        }
    }
#pragma unroll
    for (int jj = 0; jj < BISS; ++jj) {
        int j = w * BISS + jj;
        int r = j * 16 + (l >> 2);
        int ks = (l & 3) ^ (r & 3);
        offB[jj] = bbase + (long)(n0 + r) * ldb + ks * 8;
    }

    // frag read offsets (ushort units); rs = swizzled k-slot, constant per lane
    const int rs = lk ^ (lr & 3);
    int aoff[MR], boff[NR];
#pragma unroll
    for (int i = 0; i < MR; ++i) aoff[i] = (wm0 + i * 16 + lr) * 32 + rs * 8;
#pragma unroll
    for (int j = 0; j < NR; ++j) boff[j] = (wn0 + j * 16 + lr) * 32 + rs * 8;

    f32x4 acc[MR][NR] = {};

    for (int k0 = 0; k0 < K; k0 += BK) {
        if constexpr (AMODE == 0) {
#pragma unroll
            for (int jj = 0; jj < AISS; ++jj) {
                int j = w * AISS + jj;
                gload16(Ahi + offA[jj] + k0, &sA[0][j * 512]);
                gload16(Alo + offA[jj] + k0, &sA[1][j * 512]);
            }
        } else {
#pragma unroll
            for (int e = 0; e < 2; ++e) {
                int s = e * 256 + t;
                int r = s >> 2, ks = s & 3;
                const float* p = gA[e] + k0;
                float f[8];
                *(float4*)&f[0] = *(const float4*)p;
                *(float4*)&f[4] = *(const float4*)(p + 4);
                us8 hi, lo; split8(f, hi, lo);
                int q = r * 32 + (ks ^ (r & 3)) * 8;
                *(us8*)&sA[0][q] = hi;
                *(us8*)&sA[1][q] = lo;
            }
        }
#pragma unroll
        for (int jj = 0; jj < BISS; ++jj) {
            int j = w * BISS + jj;
            gload16(Bhi + offB[jj] + k0, &sB[0][j * 512]);
            gload16(Blo + offB[jj] + k0, &sB[1][j * 512]);
        }
        __syncthreads();   // compiler drains vmcnt+lgkmcnt before s_barrier

        us8 ah[MR], al[MR], bh[NR], bl[NR];
#pragma unroll
        for (int i = 0; i < MR; ++i) {
            ah[i] = *(const us8*)&sA[0][aoff[i]];
            al[i] = *(const us8*)&sA[1][aoff[i]];
        }
#pragma unroll
        for (int j = 0; j < NR; ++j) {
            bh[j] = *(const us8*)&sB[0][boff[j]];
            bl[j] = *(const us8*)&sB[1][boff[j]];
        }
#pragma unroll
        for (int i = 0; i < MR; ++i) {
            bf16x8 xh = __builtin_bit_cast(bf16x8, ah[i]);
            bf16x8 xl = __builtin_bit_cast(bf16x8, al[i]);
#pragma unroll
            for (int j = 0; j < NR; ++j) {
                bf16x8 yh = __builtin_bit_cast(bf16x8, bh[j]);
                bf16x8 yl = __builtin_bit_cast(bf16x8, bl[j]);
                acc[i][j] = __builtin_amdgcn_mfma_f32_16x16x32_bf16(xh, yh, acc[i][j], 0, 0, 0);
                acc[i][j] = __builtin_amdgcn_mfma_f32_16x16x32_bf16(xh, yl, acc[i][j], 0, 0, 0);
                acc[i][j] = __builtin_amdgcn_mfma_f32_16x16x32_bf16(xl, yh, acc[i][j], 0, 0, 0);
                if constexpr (NPROD == 4)
                    acc[i][j] = __builtin_amdgcn_mfma_f32_16x16x32_bf16(xl, yl, acc[i][j], 0, 0, 0);
            }
        }
        __syncthreads();
    }

    // Epilogue. C/D layout: col = lane&15, row = (lane>>4)*4 + reg (verified r1).
#pragma unroll
    for (int i = 0; i < MR; ++i) {
        const int mrow = m0 + wm0 + i * 16 + lk * 4;
#pragma unroll
        for (int j = 0; j < NR; ++j) {
            const int n  = wn0 + j * 16 + lr;      // col within tile
            const int nc = ncol0 + n;              // col within segment
            const float bv = bias ? bias[nc] : 0.0f;
#pragma unroll
            for (int r = 0; r < 4; ++r) {
                float v = acc[i][j][r] * scale + bv;
                if (causal && (n0 + n) > mrow + r) v = maskval;
                long co = cbase + (long)(mrow + r) * ldc + nc;
                if (Cf) Cf[co] = v;
                if (Chi) { unsigned short hh, ll; split1(v, hh, ll); Chi[co] = hh; Clo[co] = ll; }
            }
        }
    }
}

// fp32 [n] -> bf16 hi/lo, 8 elems/thread, coalesced.
__global__ __launch_bounds__(256) void split_kernel(
    const float* __restrict__ in, unsigned short* __restrict__ ohi,
    unsigned short* __restrict__ olo, long n8)
{
    long t = (long)blockIdx.x * 256 + threadIdx.x;
    if (t >= n8) return;
    const float* p = in + t * 8;
    float f[8];
    *(float4*)&f[0] = *(const float4*)p;
    *(float4*)&f[4] = *(const float4*)(p + 4);
    us8 hi, lo; split8(f, hi, lo);
    *(us8*)&ohi[t * 8] = hi;
    *(us8*)&olo[t * 8] = lo;
}

// in [K][N] fp32 (batched) -> out [N][K] bf16 hi/lo. 64x64 LDS tile.
__global__ __launch_bounds__(256) void tsp_kernel(
    const float* __restrict__ in, unsigned short* __restrict__ ohi,
    unsigned short* __restrict__ olo, int K, int N, long ibs, long obs)
{
    __shared__ float tile[64][65];
    int k0 = blockIdx.x * 64, n0 = blockIdx.y * 64;
    const float* ib = in + (long)blockIdx.z * ibs;
    ohi += (long)blockIdx.z * obs;
    olo += (long)blockIdx.z * obs;
    int t = threadIdx.x;
#pragma unroll
    for (int e = 0; e < 16; ++e) {
        int i = e * 256 + t; int r = i >> 6, c = i & 63;
        tile[r][c] = ib[(long)(k0 + r) * N + (n0 + c)];
    }
    __syncthreads();
#pragma unroll
    for (int e = 0; e < 16; ++e) {
        int i = e * 256 + t; int r = i >> 6, c = i & 63;  // out row n0+r, col k0+c
        unsigned short h, l; split1(tile[c][r], h, l);
        long o = (long)(n0 + r) * K + (k0 + c);
        ohi[o] = h; olo[o] = l;
    }
}

// RoPE over (B,L,H,64) fp32 input [4096][1024] -> bf16 hi/lo (+ optional fp32 sink).
__global__ __launch_bounds__(256) void rope_split_kernel(
    const float* __restrict__ in,
    unsigned short* __restrict__ dhi, unsigned short* __restrict__ dlo, int dld,
    float* __restrict__ f32out, int fld)
{
    int t = blockIdx.x * 256 + threadIdx.x;   // 2,097,152 threads
    int i = t & 31;
    int h = (t >> 5) & 15;
    int l = (t >> 9) & 2047;
    int b = t >> 20;
    long row = (long)b * Lc + l;

    float inv_freq = powf(10000.0f, -(float)i * (1.0f / 32.0f));
    float ang = (float)l * inv_freq;
    float s, c;
    sincosf(ang, &s, &c);

    long ia = row * 1024 + h * 64 + i;
    float x1 = in[ia], x2 = in[ia + 32];
    float o1 = x1 * c - x2 * s;
    float o2 = x2 * c + x1 * s;
    long oa = row * dld + h * 64 + i;
    unsigned short h1, l1, h2, l2;
    split1(o1, h1, l1); split1(o2, h2, l2);
    dhi[oa] = h1; dlo[oa] = l1;
    dhi[oa + 32] = h2; dlo[oa + 32] = l2;
    if (f32out) {
        long fa = row * fld + h * 64 + i;
        f32out[fa] = o1; f32out[fa + 32] = o2;
    }
}

// Row softmax over 2048-wide rows. One block (256 threads) per row.
__global__ __launch_bounds__(256) void softmax_kernel(
    const float* __restrict__ S, float* __restrict__ P)
{
    long row = blockIdx.x;
    const float* sr = S + row * Lc;
    float* pr = P + row * Lc;
    int t = threadIdx.x;

    float v[8];
    float m = -3.4e38f;
#pragma unroll
    for (int e = 0; e < 8; ++e) { v[e] = sr[t + e * 256]; m = fmaxf(m, v[e]); }
#pragma unroll
    for (int off = 32; off >= 1; off >>= 1) m = fmaxf(m, __shfl_xor(m, off));
    __shared__ float redm[4], reds[4];
    int wave = t >> 6;
    if ((t & 63) == 0) redm[wave] = m;
    __syncthreads();
    m = fmaxf(fmaxf(redm[0], redm[1]), fmaxf(redm[2], redm[3]));

    float s = 0.0f;
#pragma unroll
    for (int e = 0; e < 8; ++e) { v[e] = __expf(v[e] - m); s += v[e]; }
#pragma unroll
    for (int off = 32; off >= 1; off >>= 1) s += __shfl_xor(s, off);
    if ((t & 63) == 0) reds[wave] = s;
    __syncthreads();
    s = reds[0] + reds[1] + reds[2] + reds[3];
    float inv = 1.0f / s;
#pragma unroll
    for (int e = 0; e < 8; ++e) pr[t + e * 256] = v[e] * inv;
}

extern "C" void kernel_launch(void* const* d_in, const int* in_sizes, int n_in,
                              void* d_out, int out_size, void* d_ws, size_t ws_size,
                              hipStream_t stream)
{
    const float* x        = (const float*)d_in[0];
    const float* W_latent = (const float*)d_in[1];
    const float* W_q_down = (const float*)d_in[2];
    const float* b_q_down = (const float*)d_in[3];
    const float* W_q_up   = (const float*)d_in[4];
    const float* W_k_up   = (const float*)d_in[5];
    const float* W_v_up   = (const float*)d_in[6];
    const float* W_x_rope = (const float*)d_in[7];
    const float* W_k_rope = (const float*)d_in[8];
    const float* W_o      = (const float*)d_in[9];

    float* out      = (float*)d_out;
    float* z_out    = out + OFF_Z;
    float* kr_out   = out + OFF_KR;
    float* attn_out = out + OFF_ATTN;
    float* sc_out   = out + OFF_SC;

    // --- scratch carved from the attn output region (all dead before softmax
    //     writes attn at step 11; softmax/step-10 only touch sc region) ---
    char* scr = (char*)attn_out;
    unsigned short* xhi  = (unsigned short*)scr;                 // [4096][4096]
    unsigned short* xlo  = xhi + 16777216;
    unsigned short* zhi  = (unsigned short*)(scr + 67108864);    // [4096][1024]
    unsigned short* zlo  = zhi + 4194304;
    unsigned short* qlhi = zlo + 4194304;                        // q_lat pair
    unsigned short* qllo = qlhi + 4194304;
    float*          T    = (float*)(scr + 100663296);            // fp32 temp [4096][1024]
    unsigned short* qchi = (unsigned short*)(scr + 117440512);   // qcat pair [4096][2048]
    unsigned short* qclo = qchi + 8388608;
    unsigned short* kchi = qclo + 8388608;                       // kcat pair
    unsigned short* kclo = kchi + 8388608;
    // scratch ends at byte 184,549,376 < attn region size 536,870,912

    // --- d_ws: only buffers that must survive into steps 11-13 (80 MB) ---
    char* w8 = (char*)d_ws;
    unsigned short* Wshi = (unsigned short*)w8;                  // up to [3072][4096]
    unsigned short* Wslo = Wshi + 12582912;
    unsigned short* vThi = (unsigned short*)(w8 + 50331648);     // valT [2][1024][2048]
    unsigned short* vTlo = vThi + 4194304;
    unsigned short* hohi = (unsigned short*)(w8 + 67108864);     // head_out pair [4096][1024]
    unsigned short* holo = hohi + 4194304;

    const int M = Bc * Lc;  // 4096
    const unsigned short* nu = nullptr;
    float* nf = nullptr; unsigned short* nus = nullptr; const float* ncf = nullptr;

    // 0. x -> hi/lo
    split_kernel<<<dim3(8192), dim3(256), 0, stream>>>(x, xhi, xlo, 2097152L);

    // transposed-split weight concat for fused {1,2,3}: [3072][4096]
    tsp_kernel<<<dim3(64, 16, 1), 256, 0, stream>>>(W_latent, Wshi,           Wslo,           4096, 1024, 0, 0);
    tsp_kernel<<<dim3(64, 16, 1), 256, 0, stream>>>(W_q_down, Wshi + 4194304, Wslo + 4194304, 4096, 1024, 0, 0);
    tsp_kernel<<<dim3(64, 16, 1), 256, 0, stream>>>(W_k_rope, Wshi + 8388608, Wslo + 8388608, 4096, 1024, 0, 0);

    // F123: [z | q_lat | kr_pre] = x @ [W_latent | W_q_down | W_k_rope]
    gemm_hl<128, 3, 0><<<dim3(24, 32, 1), 256, 0, stream>>>(
        xhi, xlo, nullptr, Wshi, Wslo,
        z_out, zhi, zlo, ncf, 1024,          // seg0: z (fp32 output + pair)
        nf, qlhi, qllo, b_q_down, 1024,      // seg1: q_lat (pair, +bias)
        T, nus, nus, ncf, 1024,              // seg2: kr_pre (fp32 temp)
        M, 3072, 4096, 4096, 4096,
        0, 0, 0, 0, 0, 0, 1, 0, 1.0f, 0.0f, 10);

    // rope(k): T -> kcat cols[1024:2048] pair + kr_out fp32
    rope_split_kernel<<<dim3(8192), 256, 0, stream>>>(T, kchi + 1024, kclo + 1024, 2048, kr_out, 1024);

    // weights for fused {5,6}: [2048][1024]
    tsp_kernel<<<dim3(16, 16, 1), 256, 0, stream>>>(W_k_up, Wshi,           Wslo,           1024, 1024, 0, 0);
    tsp_kernel<<<dim3(16, 16, 1), 256, 0, stream>>>(W_v_up, Wshi + 1048576, Wslo + 1048576, 1024, 1024, 0, 0);

    // F56: [key_nope | value] = z @ [W_k_up | W_v_up]
    gemm_hl<128, 3, 0><<<dim3(16, 32, 1), 256, 0, stream>>>(
        zhi, zlo, nullptr, Wshi, Wslo,
        nf, kchi, kclo, ncf, 2048,           // seg0: key_nope -> kcat cols[0:1024]
        T, nus, nus, ncf, 1024,              // seg1: value -> T fp32
        nf, nus, nus, ncf, 0,
        M, 2048, 1024, 1024, 1024,
        0, 0, 0, 0, 0, 0, 1, 0, 1.0f, 0.0f, 10);

    // valT: val (b, l, h*64+d) -> (b, h*64+d, l) bf16 pair
    tsp_kernel<<<dim3(32, 16, 2), 256, 0, stream>>>(T, vThi, vTlo, 2048, 1024, 2097152, 2097152);

    // weights for fused {7,8}
    tsp_kernel<<<dim3(16, 16, 1), 256, 0, stream>>>(W_q_up,   Wshi,           Wslo,           1024, 1024, 0, 0);
    tsp_kernel<<<dim3(16, 16, 1), 256, 0, stream>>>(W_x_rope, Wshi + 1048576, Wslo + 1048576, 1024, 1024, 0, 0);

    // F78: [query | qr_pre] = q_lat @ [W_q_up | W_x_rope]
    gemm_hl<128, 3, 0><<<dim3(16, 32, 1), 256, 0, stream>>>(
        qlhi, qllo, nullptr, Wshi, Wslo,
        nf, qchi, qclo, ncf, 2048,           // seg0: query -> qcat cols[0:1024]
        T, nus, nus, ncf, 1024,              // seg1: qr_pre -> T fp32
        nf, nus, nus, ncf, 0,
        M, 2048, 1024, 1024, 1024,
        0, 0, 0, 0, 0, 0, 1, 0, 1.0f, 0.0f, 10);

    // rope(q): T -> qcat cols[1024:2048] pair
    rope_split_kernel<<<dim3(8192), 256, 0, stream>>>(T, qchi + 1024, qclo + 1024, 2048, nullptr, 0);

    // 10. scores = Q @ K^T / sqrt(128), causal -1e6
    gemm_hl<128, 3, 0><<<dim3(16, 16, 32), 256, 0, stream>>>(
        qchi, qclo, nullptr, kchi, kclo,
        sc_out, nus, nus, ncf, 2048,
        nf, nus, nus, ncf, 0,
        nf, nus, nus, ncf, 0,
        Lc, Lc, 128, 2048, 2048,
        4194304L, 128L, 4194304L, 128L, 67108864L, 4194304L,
        Hc, 1, 0.08838834764831845f, -1e6f, 20);

    // 11. attn_weights = softmax(scores)
    softmax_kernel<<<dim3(Bc * Hc * Lc), 256, 0, stream>>>(sc_out, attn_out);

    // 12. head_out = scores @ value  (A = masked scores, fp32 reg-split; NPROD=4)
    gemm_hl<64, 4, 1><<<dim3(1, 16, 32), 256, 0, stream>>>(
        nu, nu, sc_out, vThi, vTlo,
        nf, hohi, holo, ncf, 1024,
        nf, nus, nus, ncf, 0,
        nf, nus, nus, ncf, 0,
        Lc, 64, Lc, 2048, 2048,
        67108864L, 4194304L, 2097152L, 131072L, 2097152L, 64L,
        Hc, 0, 1.0f, 0.0f, 20);

    // W_o^T: [4096][1024]
    tsp_kernel<<<dim3(16, 64, 1), 256, 0, stream>>>(W_o, Wshi, Wslo, 1024, 4096, 0, 0);

    // 13. out = head_out @ W_o  (NPROD=4: A magnitudes ~1e7 from masked scores)
    gemm_hl<128, 4, 0><<<dim3(32, 32, 1), 256, 0, stream>>>(
        hohi, holo, nullptr, Wshi, Wslo,
        out, nus, nus, ncf, 4096,
        nf, nus, nus, ncf, 0,
        nf, nus, nus, ncf, 0,
        M, 4096, 1024, 1024, 1024,
        0, 0, 0, 0, 0, 0, 1, 0, 1.0f, 0.0f, 20);
}